// Round 7
// baseline (434.810 us; speedup 1.0000x reference)
//
#include <hip/hip_runtime.h>

typedef unsigned short u16;
typedef unsigned int u32;
typedef __bf16 bf16x8 __attribute__((ext_vector_type(8)));
typedef float f32x4 __attribute__((ext_vector_type(4)));
typedef u16 u16x8 __attribute__((ext_vector_type(8)));
typedef __attribute__((address_space(1))) const void gvoid;
typedef __attribute__((address_space(3))) void svoid;

#define T_SEQ 2048
#define NEG_INF (-__builtin_huge_valf())

__device__ __forceinline__ u16 f2bf(float f) {
  union { float f; unsigned u; } x; x.f = f;
  unsigned u = x.u;
  return (u16)((u + 0x7FFFu + ((u >> 16) & 1u)) >> 16);
}
__device__ __forceinline__ float bf2f(u16 h) {
  union { unsigned u; float f; } x; x.u = ((unsigned)h) << 16;
  return x.f;
}
__device__ __forceinline__ u32 pack_bf2(float lo, float hi) {
  u32 r;
  asm("v_cvt_pk_bf16_f32 %0, %1, %2" : "=v"(r) : "v"(lo), "v"(hi));
  return r;
}
// 16B-block XOR swizzle within a 128B row of a [64][64] u16 LDS tile.
__device__ __forceinline__ int swz16(int row, int col16) {
  int blk = (col16 >> 3) ^ (row & 7) ^ ((row >> 3) & 7);
  return row * 64 + ((blk & 7) << 3) + (col16 & 7);
}

// ---------------- cast f32 -> bf16 ----------------
__global__ __launch_bounds__(256) void cast_f32_bf16(const float* __restrict__ in,
                                                     u16* __restrict__ out, long n) {
  long i = ((long)blockIdx.x * 256 + threadIdx.x) * 4;
  if (i >= n) return;
  float4 v = *(const float4*)(in + i);
  ushort4 o;
  o.x = f2bf(v.x); o.y = f2bf(v.y); o.z = f2bf(v.z); o.w = f2bf(v.w);
  *(ushort4*)(out + i) = o;
}

// ---------------- transpose+cast: W[K][N] f32 -> WT[N][K] bf16 ----------------
__global__ __launch_bounds__(256) void transpose_cast(const float* __restrict__ W,
                                                      u16* __restrict__ WT, int K, int N) {
  __shared__ float tile[32][33];
  int nb = blockIdx.x * 32, kb = blockIdx.y * 32;
  int tx = threadIdx.x, ty = threadIdx.y;
  #pragma unroll
  for (int i = 0; i < 32; i += 8)
    tile[ty + i][tx] = W[(size_t)(kb + ty + i) * N + nb + tx];
  __syncthreads();
  #pragma unroll
  for (int i = 0; i < 32; i += 8)
    WT[(size_t)(nb + ty + i) * K + kb + tx] = f2bf(tile[tx][ty + i]);
}

// ---------------- rope cos/sin table ----------------
__global__ __launch_bounds__(256) void rope_table_k(float2* __restrict__ tab) {
  int idx = blockIdx.x * 256 + threadIdx.x;  // 2048*32
  int t = idx >> 5, d = idx & 31;
  float inv = powf(10000.0f, -(float)d / 32.0f);
  float ang = (float)t * inv;
  float s, c;
  sincosf(ang, &s, &c);
  tab[idx] = make_float2(c, s);
}

// ---------------- GEMM (m97 structure): C = A[M][K] * BT[N][K]^T ----------------
// 128x128 tile, BK=64, 4 waves (2x2 of 64x64), global_load_lds width-16, linear LDS.
// MODE 0: bf16 out. MODE 1: f32 out. MODE 2: bf16 out + fused RoPE on cols < 2560.
template<int MODE>
__global__ __launch_bounds__(256) void gemm_bt(const u16* __restrict__ A,
                                               const u16* __restrict__ BT,
                                               void* __restrict__ Cout,
                                               int M, int N, int K,
                                               const float2* __restrict__ tab) {
  __shared__ __align__(16) u16 As[128 * 64];
  __shared__ __align__(16) u16 Bs[128 * 64];
  const int tid = threadIdx.x;
  const int w = tid >> 6, lane = tid & 63;
  const int r16 = lane & 15, kg = lane >> 4;
  const size_t rowBase = (size_t)blockIdx.y * 128;
  const size_t colBase = (size_t)blockIdx.x * 128;
  const int wm = (w >> 1) * 64, wn = (w & 1) * 64;
  f32x4 acc[4][4] = {};

  const u16* Abase = A + (rowBase + w * 32 + (lane >> 3)) * (size_t)K + (lane & 7) * 8;
  const u16* Bbase = BT + (colBase + w * 32 + (lane >> 3)) * (size_t)K + (lane & 7) * 8;

  for (int k0 = 0; k0 < K; k0 += 64) {
    __syncthreads();
    #pragma unroll
    for (int i = 0; i < 4; ++i) {
      __builtin_amdgcn_global_load_lds((gvoid*)(Abase + (size_t)i * 8 * K + k0),
                                       (svoid*)(&As[(w * 32 + i * 8) * 64]), 16, 0, 0);
      __builtin_amdgcn_global_load_lds((gvoid*)(Bbase + (size_t)i * 8 * K + k0),
                                       (svoid*)(&Bs[(w * 32 + i * 8) * 64]), 16, 0, 0);
    }
    __syncthreads();
    #pragma unroll
    for (int kk = 0; kk < 2; ++kk) {
      bf16x8 af[4], bfv[4];
      #pragma unroll
      for (int mi = 0; mi < 4; ++mi)
        af[mi] = *(const bf16x8*)(&As[(wm + mi * 16 + r16) * 64 + kk * 32 + kg * 8]);
      #pragma unroll
      for (int ni = 0; ni < 4; ++ni)
        bfv[ni] = *(const bf16x8*)(&Bs[(wn + ni * 16 + r16) * 64 + kk * 32 + kg * 8]);
      __builtin_amdgcn_s_setprio(1);
      #pragma unroll
      for (int mi = 0; mi < 4; ++mi)
        #pragma unroll
        for (int ni = 0; ni < 4; ++ni)
          acc[mi][ni] = __builtin_amdgcn_mfma_f32_16x16x32_bf16(af[mi], bfv[ni], acc[mi][ni], 0, 0, 0);
      __builtin_amdgcn_s_setprio(0);
    }
  }

  if (MODE == 2 && colBase < 2560) {
    // fused RoPE: pair (d, d+32) lives in (acc[mi][p], acc[mi][p+2]), p in {0,1}
    #pragma unroll
    for (int mi = 0; mi < 4; ++mi)
      #pragma unroll
      for (int p = 0; p < 2; ++p) {
        int d = (wn + p * 16 + r16) & 63;  // 0..31
        #pragma unroll
        for (int r = 0; r < 4; ++r) {
          int t = (int)((rowBase + wm + mi * 16 + kg * 4 + r) & (T_SEQ - 1));
          float2 cs = tab[t * 32 + d];
          float x1 = acc[mi][p][r], x2 = acc[mi][p + 2][r];
          acc[mi][p][r]     = x1 * cs.x - x2 * cs.y;
          acc[mi][p + 2][r] = x2 * cs.x + x1 * cs.y;
        }
      }
  }

  #pragma unroll
  for (int mi = 0; mi < 4; ++mi)
    #pragma unroll
    for (int ni = 0; ni < 4; ++ni) {
      size_t row = rowBase + wm + mi * 16 + kg * 4;
      size_t col = colBase + wn + ni * 16 + r16;
      if (MODE == 1) {
        float* C = (float*)Cout;
        #pragma unroll
        for (int r = 0; r < 4; ++r) C[(row + r) * N + col] = acc[mi][ni][r];
      } else {
        u16* C = (u16*)Cout;
        #pragma unroll
        for (int r = 0; r < 4; ++r) C[(row + r) * N + col] = f2bf(acc[mi][ni][r]);
      }
    }
}

// ---------------- flash attention, causal, GQA — paired q-tiles for uniform work ----
// grid: (B*H=64, 8 pairs). Block (bh,p) processes q-tiles p and 15-p sequentially:
// per-block work = (p+1)+(16-p) = 17 KV tiles -> all 512 blocks uniform, no tail.
// 4 waves x 32 q-rows. KVBLK=64, K via global_load_lds (pre-swizzled src), V dbuf regs.
// S^T = mfma(K, Q): lane holds q-row -> in-register softmax.
// O^T = mfma(V^T, P^T); output ctxT[b*2048 + h*64 + d][q].
__global__ __launch_bounds__(256) void attn_fwd(const u16* __restrict__ QKV,
                                                u16* __restrict__ ctxT) {
  const int bh = blockIdx.x, pr = blockIdx.y;
  const int b = bh >> 5, h = bh & 31, g = h >> 2;
  const int tid = threadIdx.x, w = tid >> 6, lane = tid & 63;
  const int r16 = lane & 15, kg = lane >> 4;
  const int LD = 3072;

  const u16* Qp = QKV + (size_t)b * T_SEQ * LD + h * 64;
  const u16* Kp = QKV + (size_t)b * T_SEQ * LD + 2048 + g * 64;
  const u16* Vp = QKV + (size_t)b * T_SEQ * LD + 2560 + g * 64;

  __shared__ __align__(16) u16 Kt[2][64 * 64];
  __shared__ __align__(16) u16 Vt[2][64 * 64];   // Vt[d][kv], swizzled

  const float SCALE = 0.18033688f;  // 0.125 * log2(e)
  const int srow = tid >> 3, sc8 = tid & 7;
  const int klr = (lane >> 3);          // 0..7 within 8-row chunk
  const int kblk = lane & 7;

  for (int hf = 0; hf < 2; ++hf) {
    const int qt = hf ? (15 - pr) : pr;
    const int qbase = qt * 128, wq = qbase + w * 32;

    // Q fragments (B-operand: col=q=r16, k=d=kg*8+j)
    bf16x8 qf[2][2];
    #pragma unroll
    for (int mi = 0; mi < 2; ++mi)
      #pragma unroll
      for (int ks = 0; ks < 2; ++ks)
        qf[mi][ks] = *(const bf16x8*)(Qp + (size_t)(wq + mi * 16 + r16) * LD + ks * 32 + kg * 8);

    f32x4 acc[4][2] = {};   // [di][mi]: O^T[d=di*16+kg*4+r][q=wq+mi*16+r16]
    float m_i[2] = {NEG_INF, NEG_INF}, l_i[2] = {0.0f, 0.0f};
    const int nkt = (qbase + 128) >> 6;

    // ---- prologue: stage tile 0 into buf 0 ----
    {
      #pragma unroll
      for (int i = 0; i < 2; ++i) {
        int lr = w * 16 + i * 8 + klr;
        int sb = kblk ^ ((lr & 7) ^ ((lr >> 3) & 7));
        __builtin_amdgcn_global_load_lds((gvoid*)(Kp + (size_t)lr * LD + sb * 8),
                                         (svoid*)(&Kt[0][(w * 16 + i * 8) * 64]), 16, 0, 0);
      }
      bf16x8 v0 = *(const bf16x8*)(Vp + (size_t)(2 * srow) * LD + sc8 * 8);
      bf16x8 v1 = *(const bf16x8*)(Vp + (size_t)(2 * srow + 1) * LD + sc8 * 8);
      const u16* va = (const u16*)&v0;
      const u16* vb = (const u16*)&v1;
      #pragma unroll
      for (int j = 0; j < 8; ++j)
        *(u32*)(&Vt[0][swz16(sc8 * 8 + j, 2 * srow)]) = (u32)va[j] | ((u32)vb[j] << 16);
      __syncthreads();
    }

    for (int kt = 0; kt < nkt; ++kt) {
      const int kvb = kt << 6;
      const int cur = kt & 1;
      const bool st = (kt + 1 < nkt);
      bf16x8 v0, v1;
      if (st) {
        // prefetch tile kt+1: K via gload_lds into buf cur^1, V into regs
        #pragma unroll
        for (int i = 0; i < 2; ++i) {
          int lr = w * 16 + i * 8 + klr;
          int sb = kblk ^ ((lr & 7) ^ ((lr >> 3) & 7));
          __builtin_amdgcn_global_load_lds((gvoid*)(Kp + (size_t)(kvb + 64 + lr) * LD + sb * 8),
                                           (svoid*)(&Kt[cur ^ 1][(w * 16 + i * 8) * 64]), 16, 0, 0);
        }
        v0 = *(const bf16x8*)(Vp + (size_t)(kvb + 64 + 2 * srow) * LD + sc8 * 8);
        v1 = *(const bf16x8*)(Vp + (size_t)(kvb + 64 + 2 * srow + 1) * LD + sc8 * 8);
      }

      if (kvb <= wq + 31) {
        // S^T = K * Q^T  (64 kv x 32 q)
        f32x4 stv[4][2] = {};
        #pragma unroll
        for (int ks = 0; ks < 2; ++ks) {
          bf16x8 kf[4];
          #pragma unroll
          for (int ni = 0; ni < 4; ++ni)
            kf[ni] = *(const bf16x8*)(&Kt[cur][swz16(ni * 16 + r16, ks * 32 + kg * 8)]);
          __builtin_amdgcn_s_setprio(1);
          #pragma unroll
          for (int ni = 0; ni < 4; ++ni)
            #pragma unroll
            for (int mi = 0; mi < 2; ++mi)
              stv[ni][mi] = __builtin_amdgcn_mfma_f32_16x16x32_bf16(kf[ni], qf[mi][ks], stv[ni][mi], 0, 0, 0);
          __builtin_amdgcn_s_setprio(0);
        }

        // causal mask: only the wave's diagonal tile needs it
        if (kvb + 63 > wq) {
          #pragma unroll
          for (int mi = 0; mi < 2; ++mi) {
            const int q = wq + mi * 16 + r16;
            #pragma unroll
            for (int ni = 0; ni < 4; ++ni)
              #pragma unroll
              for (int r = 0; r < 4; ++r) {
                int kv = kvb + ni * 16 + kg * 4 + r;
                if (kv > q) stv[ni][mi][r] = NEG_INF;
              }
          }
        }

        // row max (partial in-lane, then 2 shfl over kg groups)
        float tmx[2];
        #pragma unroll
        for (int mi = 0; mi < 2; ++mi) {
          float pm = NEG_INF;
          #pragma unroll
          for (int ni = 0; ni < 4; ++ni)
            #pragma unroll
            for (int r = 0; r < 4; ++r) pm = fmaxf(pm, stv[ni][mi][r]);
          pm = fmaxf(pm, __shfl_xor(pm, 16, 64));
          pm = fmaxf(pm, __shfl_xor(pm, 32, 64));
          tmx[mi] = pm;
        }
        // defer-max (T13): rescale only if some row grew past threshold
        bool upd = ((tmx[0] - m_i[0]) * SCALE > 8.0f) || ((tmx[1] - m_i[1]) * SCALE > 8.0f);
        if (__any(upd)) {
          #pragma unroll
          for (int mi = 0; mi < 2; ++mi) {
            float mnew = fmaxf(m_i[mi], tmx[mi]);
            float alpha = exp2f((m_i[mi] - mnew) * SCALE);
            m_i[mi] = mnew;
            l_i[mi] *= alpha;
            #pragma unroll
            for (int di = 0; di < 4; ++di)
              #pragma unroll
              for (int r = 0; r < 4; ++r) acc[di][mi][r] *= alpha;
          }
        }

        // P = exp2(s*SCALE - m*SCALE), pack, row-sum
        u32 pkk[2][4][2];
        #pragma unroll
        for (int mi = 0; mi < 2; ++mi) {
          float nm = m_i[mi] * SCALE;
          float rs = 0.0f;
          #pragma unroll
          for (int ni = 0; ni < 4; ++ni) {
            float p0 = exp2f(fmaf(stv[ni][mi][0], SCALE, -nm));
            float p1 = exp2f(fmaf(stv[ni][mi][1], SCALE, -nm));
            float p2 = exp2f(fmaf(stv[ni][mi][2], SCALE, -nm));
            float p3 = exp2f(fmaf(stv[ni][mi][3], SCALE, -nm));
            rs += (p0 + p1) + (p2 + p3);
            pkk[mi][ni][0] = pack_bf2(p0, p1);
            pkk[mi][ni][1] = pack_bf2(p2, p3);
          }
          rs += __shfl_xor(rs, 16, 64);
          rs += __shfl_xor(rs, 32, 64);
          l_i[mi] += rs;
        }

        // O^T += V^T * P^T ; P^T B-frag via cross-lane redistribution
        #pragma unroll
        for (int ks = 0; ks < 2; ++ks) {
          bf16x8 vfr[4];
          #pragma unroll
          for (int di = 0; di < 4; ++di)
            vfr[di] = *(const bf16x8*)(&Vt[cur][swz16(di * 16 + r16, ks * 32 + kg * 8)]);
          const int s0 = (kg & 1) * 32 + r16;
          const int s1 = s0 + 16;
          const bool hi = (kg >> 1) != 0;
          #pragma unroll
          for (int mi = 0; mi < 2; ++mi) {
            u32 a0 = __shfl(pkk[mi][2 * ks][0], s0, 64);
            u32 b0 = __shfl(pkk[mi][2 * ks + 1][0], s0, 64);
            u32 a1 = __shfl(pkk[mi][2 * ks][1], s0, 64);
            u32 b1 = __shfl(pkk[mi][2 * ks + 1][1], s0, 64);
            u32 a2 = __shfl(pkk[mi][2 * ks][0], s1, 64);
            u32 b2 = __shfl(pkk[mi][2 * ks + 1][0], s1, 64);
            u32 a3 = __shfl(pkk[mi][2 * ks][1], s1, 64);
            u32 b3 = __shfl(pkk[mi][2 * ks + 1][1], s1, 64);
            union { u32 u[4]; bf16x8 v; } pu;
            pu.u[0] = hi ? b0 : a0;
            pu.u[1] = hi ? b1 : a1;
            pu.u[2] = hi ? b2 : a2;
            pu.u[3] = hi ? b3 : a3;
            __builtin_amdgcn_s_setprio(1);
            #pragma unroll
            for (int di = 0; di < 4; ++di)
              acc[di][mi] = __builtin_amdgcn_mfma_f32_16x16x32_bf16(vfr[di], pu.v, acc[di][mi], 0, 0, 0);
            __builtin_amdgcn_s_setprio(0);
          }
        }
      }

      if (st) {
        // write prefetched V into buf cur^1 (compiler inserts vmcnt wait for v0/v1)
        const u16* va = (const u16*)&v0;
        const u16* vb = (const u16*)&v1;
        #pragma unroll
        for (int j = 0; j < 8; ++j)
          *(u32*)(&Vt[cur ^ 1][swz16(sc8 * 8 + j, 2 * srow)]) = (u32)va[j] | ((u32)vb[j] << 16);
      }
      __syncthreads();  // drains vmcnt (gload_lds) + lgkm before next tile
    }

    // epilogue: ctxT[b*2048 + h*64 + d][q] = O^T / l
    float inv[2] = {1.0f / l_i[0], 1.0f / l_i[1]};
    #pragma unroll
    for (int di = 0; di < 4; ++di)
      #pragma unroll
      for (int mi = 0; mi < 2; ++mi)
        #pragma unroll
        for (int r = 0; r < 4; ++r) {
          size_t row = (size_t)(b * 2048 + h * 64 + di * 16 + kg * 4 + r);
          ctxT[row * 2048 + wq + mi * 16 + r16] = f2bf(acc[di][mi][r] * inv[mi]);
        }
    // next half's prologue writes Kt[0]/Vt[0]; last loop barrier already protects it
  }
}

// ---------------- host ----------------
extern "C" void kernel_launch(void* const* d_in, const int* in_sizes, int n_in,
                              void* d_out, int out_size, void* d_ws, size_t ws_size,
                              hipStream_t stream) {
  const float* x  = (const float*)d_in[0];
  const float* Wq = (const float*)d_in[1];
  const float* Wk = (const float*)d_in[2];
  const float* Wv = (const float*)d_in[3];
  const float* Wo = (const float*)d_in[4];
  float* out = (float*)d_out;
  char* ws = (char*)d_ws;

  u16* xb     = (u16*)(ws);                    // 4096x2048 bf16 : 16777216
  u16* QKVb   = (u16*)(ws + 16777216);         // 4096x3072      : 25165824
  u16* ctxT   = (u16*)(ws + 41943040);         // 4096x2048      : 16777216
  u16* WqkvT  = (u16*)(ws + 58720256);         // 3072x2048      : 12582912
  u16* WoT    = (u16*)(ws + 71303168);         // 2048x2048      : 8388608
  float2* tab = (float2*)(ws + 79691776);      // 2048x32 float2 : 524288

  cast_f32_bf16<<<8192, 256, 0, stream>>>(x, xb, 8388608L);
  rope_table_k<<<256, 256, 0, stream>>>(tab);
  // WqkvT rows: [0,2048) = Wq^T, [2048,2560) = Wk^T, [2560,3072) = Wv^T
  transpose_cast<<<dim3(64, 64), dim3(32, 8), 0, stream>>>(Wq, WqkvT, 2048, 2048);
  transpose_cast<<<dim3(16, 64), dim3(32, 8), 0, stream>>>(Wk, WqkvT + 2048L * 2048, 2048, 512);
  transpose_cast<<<dim3(16, 64), dim3(32, 8), 0, stream>>>(Wv, WqkvT + 2560L * 2048, 2048, 512);
  transpose_cast<<<dim3(64, 64), dim3(32, 8), 0, stream>>>(Wo, WoT, 2048, 2048);

  // fused QKV projection + RoPE epilogue: [4096 x 3072]
  gemm_bt<2><<<dim3(24, 32), 256, 0, stream>>>(xb, WqkvT, QKVb, 4096, 3072, 2048, tab);

  attn_fwd<<<dim3(64, 8), 256, 0, stream>>>(QKVb, ctxT);

  gemm_bt<1><<<dim3(16, 32), 256, 0, stream>>>(ctxT, WoT, out, 4096, 2048, 2048, nullptr);
}

// Round 9
// 395.299 us; speedup vs baseline: 1.1000x; 1.1000x over previous
//
#include <hip/hip_runtime.h>

typedef unsigned short u16;
typedef unsigned int u32;
typedef __bf16 bf16x8 __attribute__((ext_vector_type(8)));
typedef float f32x4 __attribute__((ext_vector_type(4)));
typedef u16 u16x4 __attribute__((ext_vector_type(4)));
typedef __attribute__((address_space(1))) const void gvoid;
typedef __attribute__((address_space(3))) void svoid;

#define T_SEQ 2048
#define NEG_INF (-__builtin_huge_valf())

__device__ __forceinline__ u16 f2bf(float f) {
  union { float f; unsigned u; } x; x.f = f;
  unsigned u = x.u;
  return (u16)((u + 0x7FFFu + ((u >> 16) & 1u)) >> 16);
}
__device__ __forceinline__ u32 pack_bf2(float lo, float hi) {
  u32 r;
  asm("v_cvt_pk_bf16_f32 %0, %1, %2" : "=v"(r) : "v"(lo), "v"(hi));
  return r;
}
// 16B-block XOR swizzle within a 128B row of a [64][64] u16 LDS tile.
__device__ __forceinline__ int swz16(int row, int col16) {
  int blk = (col16 >> 3) ^ (row & 7) ^ ((row >> 3) & 7);
  return row * 64 + ((blk & 7) << 3) + (col16 & 7);
}

// ---------------- cast f32 -> bf16 ----------------
__global__ __launch_bounds__(256) void cast_f32_bf16(const float* __restrict__ in,
                                                     u16* __restrict__ out, long n) {
  long i = ((long)blockIdx.x * 256 + threadIdx.x) * 4;
  if (i >= n) return;
  float4 v = *(const float4*)(in + i);
  ushort4 o;
  o.x = f2bf(v.x); o.y = f2bf(v.y); o.z = f2bf(v.z); o.w = f2bf(v.w);
  *(ushort4*)(out + i) = o;
}

// ---------------- transpose+cast: W[K][N] f32 -> WT[N][K] bf16 ----------------
__global__ __launch_bounds__(256) void transpose_cast(const float* __restrict__ W,
                                                      u16* __restrict__ WT, int K, int N) {
  __shared__ float tile[32][33];
  int nb = blockIdx.x * 32, kb = blockIdx.y * 32;
  int tx = threadIdx.x, ty = threadIdx.y;
  #pragma unroll
  for (int i = 0; i < 32; i += 8)
    tile[ty + i][tx] = W[(size_t)(kb + ty + i) * N + nb + tx];
  __syncthreads();
  #pragma unroll
  for (int i = 0; i < 32; i += 8)
    WT[(size_t)(nb + ty + i) * K + kb + tx] = f2bf(tile[tx][ty + i]);
}

// ---------------- rope cos/sin table ----------------
__global__ __launch_bounds__(256) void rope_table_k(float2* __restrict__ tab) {
  int idx = blockIdx.x * 256 + threadIdx.x;  // 2048*32
  int t = idx >> 5, d = idx & 31;
  float inv = powf(10000.0f, -(float)d / 32.0f);
  float ang = (float)t * inv;
  float s, c;
  sincosf(ang, &s, &c);
  tab[idx] = make_float2(c, s);
}

// ---------------- GEMM (m97 structure): C = A[M][K] * BT[N][K]^T ----------------
// 128x128 tile, BK=64, 4 waves (2x2 of 64x64), global_load_lds width-16, linear LDS.
// MODE 0: bf16 out. MODE 1: f32 out. MODE 2: bf16 out + fused RoPE on cols < 2560.
template<int MODE>
__global__ __launch_bounds__(256) void gemm_bt(const u16* __restrict__ A,
                                               const u16* __restrict__ BT,
                                               void* __restrict__ Cout,
                                               int M, int N, int K,
                                               const float2* __restrict__ tab) {
  __shared__ __align__(16) u16 As[128 * 64];
  __shared__ __align__(16) u16 Bs[128 * 64];
  const int tid = threadIdx.x;
  const int w = tid >> 6, lane = tid & 63;
  const int r16 = lane & 15, kg = lane >> 4;
  const size_t rowBase = (size_t)blockIdx.y * 128;
  const size_t colBase = (size_t)blockIdx.x * 128;
  const int wm = (w >> 1) * 64, wn = (w & 1) * 64;
  f32x4 acc[4][4] = {};

  const u16* Abase = A + (rowBase + w * 32 + (lane >> 3)) * (size_t)K + (lane & 7) * 8;
  const u16* Bbase = BT + (colBase + w * 32 + (lane >> 3)) * (size_t)K + (lane & 7) * 8;

  for (int k0 = 0; k0 < K; k0 += 64) {
    __syncthreads();
    #pragma unroll
    for (int i = 0; i < 4; ++i) {
      __builtin_amdgcn_global_load_lds((gvoid*)(Abase + (size_t)i * 8 * K + k0),
                                       (svoid*)(&As[(w * 32 + i * 8) * 64]), 16, 0, 0);
      __builtin_amdgcn_global_load_lds((gvoid*)(Bbase + (size_t)i * 8 * K + k0),
                                       (svoid*)(&Bs[(w * 32 + i * 8) * 64]), 16, 0, 0);
    }
    __syncthreads();
    #pragma unroll
    for (int kk = 0; kk < 2; ++kk) {
      bf16x8 af[4], bfv[4];
      #pragma unroll
      for (int mi = 0; mi < 4; ++mi)
        af[mi] = *(const bf16x8*)(&As[(wm + mi * 16 + r16) * 64 + kk * 32 + kg * 8]);
      #pragma unroll
      for (int ni = 0; ni < 4; ++ni)
        bfv[ni] = *(const bf16x8*)(&Bs[(wn + ni * 16 + r16) * 64 + kk * 32 + kg * 8]);
      __builtin_amdgcn_s_setprio(1);
      #pragma unroll
      for (int mi = 0; mi < 4; ++mi)
        #pragma unroll
        for (int ni = 0; ni < 4; ++ni)
          acc[mi][ni] = __builtin_amdgcn_mfma_f32_16x16x32_bf16(af[mi], bfv[ni], acc[mi][ni], 0, 0, 0);
      __builtin_amdgcn_s_setprio(0);
    }
  }

  if (MODE == 2 && colBase < 2560) {
    // fused RoPE: pair (d, d+32) lives in (acc[mi][p], acc[mi][p+2]), p in {0,1}
    #pragma unroll
    for (int mi = 0; mi < 4; ++mi)
      #pragma unroll
      for (int p = 0; p < 2; ++p) {
        int d = (wn + p * 16 + r16) & 63;  // 0..31
        #pragma unroll
        for (int r = 0; r < 4; ++r) {
          int t = (int)((rowBase + wm + mi * 16 + kg * 4 + r) & (T_SEQ - 1));
          float2 cs = tab[t * 32 + d];
          float x1 = acc[mi][p][r], x2 = acc[mi][p + 2][r];
          acc[mi][p][r]     = x1 * cs.x - x2 * cs.y;
          acc[mi][p + 2][r] = x2 * cs.x + x1 * cs.y;
        }
      }
  }

  #pragma unroll
  for (int mi = 0; mi < 4; ++mi)
    #pragma unroll
    for (int ni = 0; ni < 4; ++ni) {
      size_t row = rowBase + wm + mi * 16 + kg * 4;
      size_t col = colBase + wn + ni * 16 + r16;
      if (MODE == 1) {
        float* C = (float*)Cout;
        #pragma unroll
        for (int r = 0; r < 4; ++r) C[(row + r) * N + col] = acc[mi][ni][r];
      } else {
        u16* C = (u16*)Cout;
        #pragma unroll
        for (int r = 0; r < 4; ++r) C[(row + r) * N + col] = f2bf(acc[mi][ni][r]);
      }
    }
}

// ---------------- flash attention, causal, GQA — 8 waves x 16 q-rows, paired tiles --
// grid: (B*H=64, 8 pairs) x 512 threads. Block (bh,p) does q-tiles p and 15-p:
// uniform (2p+2)+(2(15-p)+2) = 34 KV-tiles/block; 2 blocks/CU x 8 waves = 16 waves/CU.
// Wave w owns 16 q-rows (wq = qbase + w*16). KVBLK=64.
// K via global_load_lds (pre-swizzled source), V reg-staged dbuf.
// S^T = mfma(K, Q): lane holds one q-row -> in-register softmax (2 shfl).
// O^T = mfma(V^T, P^T); output ctxT[b*2048 + h*64 + d][q].
__global__ __launch_bounds__(512, 4) void attn_fwd(const u16* __restrict__ QKV,
                                                   u16* __restrict__ ctxT) {
  const int bh = blockIdx.x, pr = blockIdx.y;
  const int b = bh >> 5, h = bh & 31, g = h >> 2;
  const int tid = threadIdx.x, w = tid >> 6, lane = tid & 63;
  const int r16 = lane & 15, kg = lane >> 4;
  const int LD = 3072;

  const u16* Qp = QKV + (size_t)b * T_SEQ * LD + h * 64;
  const u16* Kp = QKV + (size_t)b * T_SEQ * LD + 2048 + g * 64;
  const u16* Vp = QKV + (size_t)b * T_SEQ * LD + 2560 + g * 64;

  __shared__ __align__(16) u16 Kt[2][64 * 64];
  __shared__ __align__(16) u16 Vt[2][64 * 64];   // Vt[d][kv], swizzled

  const float SCALE = 0.18033688f;  // 0.125 * log2(e)
  // V staging: thread -> kv-pair (srow) x 4-d group (sc4)
  const int srow = tid >> 4, sc4 = tid & 15;
  // K staging: wave w stages rows w*8..w*8+7, 1 global_load_lds per wave
  const int klr = w * 8 + (lane >> 3);
  const int ksb = (lane & 7) ^ (klr & 7) ^ ((klr >> 3) & 7);  // pre-swizzled 16B block

  for (int hf = 0; hf < 2; ++hf) {
    const int qt = hf ? (15 - pr) : pr;
    const int qbase = qt * 128, wq = qbase + w * 16;
    const int nkt = 2 * qt + 2;   // (qbase + 128) / 64 — FULL causal KV range

    // Q fragments (B-operand: col=q=r16, k=d=kg*8+j)
    bf16x8 qf[2];
    #pragma unroll
    for (int ks = 0; ks < 2; ++ks)
      qf[ks] = *(const bf16x8*)(Qp + (size_t)(wq + r16) * LD + ks * 32 + kg * 8);

    f32x4 acc[4] = {};   // [di]: O^T[d=di*16+kg*4+r][q=wq+r16]
    float m_i = NEG_INF, l_i = 0.0f;

    // ---- prologue: stage tile 0 into buf 0 ----
    {
      __builtin_amdgcn_global_load_lds((gvoid*)(Kp + (size_t)klr * LD + ksb * 8),
                                       (svoid*)(&Kt[0][w * 512]), 16, 0, 0);
      u16x4 a0 = *(const u16x4*)(Vp + (size_t)(2 * srow) * LD + sc4 * 4);
      u16x4 a1 = *(const u16x4*)(Vp + (size_t)(2 * srow + 1) * LD + sc4 * 4);
      #pragma unroll
      for (int j = 0; j < 4; ++j)
        *(u32*)(&Vt[0][swz16(sc4 * 4 + j, 2 * srow)]) = (u32)a0[j] | ((u32)a1[j] << 16);
      __syncthreads();
    }

    for (int kt = 0; kt < nkt; ++kt) {
      const int kvb = kt << 6;
      const int cur = kt & 1;
      const bool st = (kt + 1 < nkt);
      u16x4 a0, a1;
      if (st) {
        __builtin_amdgcn_global_load_lds((gvoid*)(Kp + (size_t)(kvb + 64 + klr) * LD + ksb * 8),
                                         (svoid*)(&Kt[cur ^ 1][w * 512]), 16, 0, 0);
        a0 = *(const u16x4*)(Vp + (size_t)(kvb + 64 + 2 * srow) * LD + sc4 * 4);
        a1 = *(const u16x4*)(Vp + (size_t)(kvb + 64 + 2 * srow + 1) * LD + sc4 * 4);
      }

      if (kvb <= wq + 15) {   // wave-uniform
        // S^T = K * Q^T  (64 kv x 16 q)
        f32x4 stv[4] = {};
        #pragma unroll
        for (int ks = 0; ks < 2; ++ks) {
          bf16x8 kf[4];
          #pragma unroll
          for (int ni = 0; ni < 4; ++ni)
            kf[ni] = *(const bf16x8*)(&Kt[cur][swz16(ni * 16 + r16, ks * 32 + kg * 8)]);
          __builtin_amdgcn_s_setprio(1);
          #pragma unroll
          for (int ni = 0; ni < 4; ++ni)
            stv[ni] = __builtin_amdgcn_mfma_f32_16x16x32_bf16(kf[ni], qf[ks], stv[ni], 0, 0, 0);
          __builtin_amdgcn_s_setprio(0);
        }

        // causal mask: only the diagonal-region tile needs it
        if (kvb + 63 > wq) {
          const int q = wq + r16;
          #pragma unroll
          for (int ni = 0; ni < 4; ++ni)
            #pragma unroll
            for (int r = 0; r < 4; ++r)
              if (kvb + ni * 16 + kg * 4 + r > q) stv[ni][r] = NEG_INF;
        }

        // row max (in-lane + 2 shfl over kg groups)
        float pm = NEG_INF;
        #pragma unroll
        for (int ni = 0; ni < 4; ++ni)
          #pragma unroll
          for (int r = 0; r < 4; ++r) pm = fmaxf(pm, stv[ni][r]);
        pm = fmaxf(pm, __shfl_xor(pm, 16, 64));
        pm = fmaxf(pm, __shfl_xor(pm, 32, 64));
        // defer-max (T13)
        if (__any((pm - m_i) * SCALE > 8.0f)) {
          float mnew = fmaxf(m_i, pm);
          float alpha = exp2f((m_i - mnew) * SCALE);
          m_i = mnew;
          l_i *= alpha;
          #pragma unroll
          for (int di = 0; di < 4; ++di)
            #pragma unroll
            for (int r = 0; r < 4; ++r) acc[di][r] *= alpha;
        }

        // P = exp2(s*SCALE - m*SCALE), pack, row-sum
        u32 pkk[4][2];
        float nm = m_i * SCALE;
        float rs = 0.0f;
        #pragma unroll
        for (int ni = 0; ni < 4; ++ni) {
          float p0 = exp2f(fmaf(stv[ni][0], SCALE, -nm));
          float p1 = exp2f(fmaf(stv[ni][1], SCALE, -nm));
          float p2 = exp2f(fmaf(stv[ni][2], SCALE, -nm));
          float p3 = exp2f(fmaf(stv[ni][3], SCALE, -nm));
          rs += (p0 + p1) + (p2 + p3);
          pkk[ni][0] = pack_bf2(p0, p1);
          pkk[ni][1] = pack_bf2(p2, p3);
        }
        rs += __shfl_xor(rs, 16, 64);
        rs += __shfl_xor(rs, 32, 64);
        l_i += rs;

        // O^T += V^T * P^T ; P^T B-frag via cross-lane redistribution
        #pragma unroll
        for (int ks = 0; ks < 2; ++ks) {
          bf16x8 vfr[4];
          #pragma unroll
          for (int di = 0; di < 4; ++di)
            vfr[di] = *(const bf16x8*)(&Vt[cur][swz16(di * 16 + r16, ks * 32 + kg * 8)]);
          const int s0 = (kg & 1) * 32 + r16;
          const int s1 = s0 + 16;
          const bool hi = (kg >> 1) != 0;
          u32 c0 = __shfl(pkk[2 * ks][0], s0, 64);
          u32 d0 = __shfl(pkk[2 * ks + 1][0], s0, 64);
          u32 c1 = __shfl(pkk[2 * ks][1], s0, 64);
          u32 d1 = __shfl(pkk[2 * ks + 1][1], s0, 64);
          u32 c2 = __shfl(pkk[2 * ks][0], s1, 64);
          u32 d2 = __shfl(pkk[2 * ks + 1][0], s1, 64);
          u32 c3 = __shfl(pkk[2 * ks][1], s1, 64);
          u32 d3 = __shfl(pkk[2 * ks + 1][1], s1, 64);
          union { u32 u[4]; bf16x8 v; } pu;
          pu.u[0] = hi ? d0 : c0;
          pu.u[1] = hi ? d1 : c1;
          pu.u[2] = hi ? d2 : c2;
          pu.u[3] = hi ? d3 : c3;
          __builtin_amdgcn_s_setprio(1);
          #pragma unroll
          for (int di = 0; di < 4; ++di)
            acc[di] = __builtin_amdgcn_mfma_f32_16x16x32_bf16(vfr[di], pu.v, acc[di], 0, 0, 0);
          __builtin_amdgcn_s_setprio(0);
        }
      }

      if (st) {
        // write prefetched V into buf cur^1 (compiler inserts vmcnt wait)
        #pragma unroll
        for (int j = 0; j < 4; ++j)
          *(u32*)(&Vt[cur ^ 1][swz16(sc4 * 4 + j, 2 * srow)]) = (u32)a0[j] | ((u32)a1[j] << 16);
      }
      __syncthreads();  // drains vmcnt (gload_lds) + lgkm before next tile
    }

    // epilogue: ctxT[b*2048 + h*64 + d][q] = O^T / l  (no LDS reads after last barrier)
    float inv = 1.0f / l_i;
    #pragma unroll
    for (int di = 0; di < 4; ++di)
      #pragma unroll
      for (int r = 0; r < 4; ++r) {
        size_t row = (size_t)(b * 2048 + h * 64 + di * 16 + kg * 4 + r);
        ctxT[row * 2048 + wq + r16] = f2bf(acc[di][r] * inv);
      }
  }
}

// ---------------- host ----------------
extern "C" void kernel_launch(void* const* d_in, const int* in_sizes, int n_in,
                              void* d_out, int out_size, void* d_ws, size_t ws_size,
                              hipStream_t stream) {
  const float* x  = (const float*)d_in[0];
  const float* Wq = (const float*)d_in[1];
  const float* Wk = (const float*)d_in[2];
  const float* Wv = (const float*)d_in[3];
  const float* Wo = (const float*)d_in[4];
  float* out = (float*)d_out;
  char* ws = (char*)d_ws;

  u16* xb     = (u16*)(ws);                    // 4096x2048 bf16 : 16777216
  u16* QKVb   = (u16*)(ws + 16777216);         // 4096x3072      : 25165824
  u16* ctxT   = (u16*)(ws + 41943040);         // 4096x2048      : 16777216
  u16* WqkvT  = (u16*)(ws + 58720256);         // 3072x2048      : 12582912
  u16* WoT    = (u16*)(ws + 71303168);         // 2048x2048      : 8388608
  float2* tab = (float2*)(ws + 79691776);      // 2048x32 float2 : 524288

  cast_f32_bf16<<<8192, 256, 0, stream>>>(x, xb, 8388608L);
  rope_table_k<<<256, 256, 0, stream>>>(tab);
  // WqkvT rows: [0,2048) = Wq^T, [2048,2560) = Wk^T, [2560,3072) = Wv^T
  transpose_cast<<<dim3(64, 64), dim3(32, 8), 0, stream>>>(Wq, WqkvT, 2048, 2048);
  transpose_cast<<<dim3(16, 64), dim3(32, 8), 0, stream>>>(Wk, WqkvT + 2048L * 2048, 2048, 512);
  transpose_cast<<<dim3(16, 64), dim3(32, 8), 0, stream>>>(Wv, WqkvT + 2560L * 2048, 2048, 512);
  transpose_cast<<<dim3(64, 64), dim3(32, 8), 0, stream>>>(Wo, WoT, 2048, 2048);

  // fused QKV projection + RoPE epilogue: [4096 x 3072]
  gemm_bt<2><<<dim3(24, 32), 256, 0, stream>>>(xb, WqkvT, QKVb, 4096, 3072, 2048, tab);

  attn_fwd<<<dim3(64, 8), 512, 0, stream>>>(QKVb, ctxT);

  gemm_bt<1><<<dim3(16, 32), 256, 0, stream>>>(ctxT, WoT, out, 4096, 2048, 2048, nullptr);
}